// Round 4
// baseline (198.888 us; speedup 1.0000x reference)
//
#include <hip/hip_runtime.h>
#include <hip/hip_bf16.h>

#define AN 256
#define BN 64
#define DN 768
#define LN 2
#define G1N 4
#define G2N 8

typedef __attribute__((ext_vector_type(8))) short short8;   // 8 bf16
typedef __attribute__((ext_vector_type(4))) short bf16x4;   // 4 bf16
typedef __attribute__((ext_vector_type(4))) float floatx4;  // MFMA acc

static __device__ __forceinline__ unsigned short f2bf(float f) {
    union { float f; unsigned int u; } v; v.f = f;
    unsigned int r = v.u + 0x7FFF + ((v.u >> 16) & 1);  // RNE
    return (unsigned short)(r >> 16);
}

// ---------------------------------------------------------------------------
// kb: bucket annotators by g1 and g2; bc[a,l] = b2[g2(a)].Wh[a][:,l] + bh[a,l];
// pooled -> bf16. grid = 8 blocks x 256.
// ---------------------------------------------------------------------------
__global__ __launch_bounds__(256) void kb(
    const float* __restrict__ pooled, const float* __restrict__ b2,
    const float* __restrict__ Wh, const float* __restrict__ bh,
    const int* __restrict__ g1i, const int* __restrict__ g2i,
    int* __restrict__ n1, int* __restrict__ n2,
    int* __restrict__ list1, int* __restrict__ list2,
    float* __restrict__ bc, unsigned short* __restrict__ pooled_bf)
{
    const int tid = threadIdx.x, bx = blockIdx.x;

    if (bx == 0) {
        __shared__ int c1s[G1N], c2s[G2N];
        if (tid < G1N) c1s[tid] = 0;
        if (tid < G2N) c2s[tid] = 0;
        __syncthreads();
        {
            int a = tid;                       // 256 threads = 256 annotators
            int gv1 = g1i[a], gv2 = g2i[a];
            int s1 = atomicAdd(&c1s[gv1], 1); list1[gv1 * 256 + s1] = a;
            int s2 = atomicAdd(&c2s[gv2], 1); list2[gv2 * 256 + s2] = a;
        }
        __syncthreads();
        if (tid < G1N) n1[tid] = c1s[tid];
        if (tid < G2N) n2[tid] = c2s[tid];
    }

    // pooled conversion slice: 49152 elems / 8 blocks
    for (int i = bx * 6144 + tid; i < bx * 6144 + 6144; i += 256)
        pooled_bf[i] = f2bf(pooled[i]);

    // bc: 32 annotators per block, 8 threads per annotator
    const int aa = tid >> 3, j = tid & 7;
    const int a = bx * 32 + aa;
    const int gv2 = g2i[a];
    const float* whp = Wh + (size_t)a * (DN * LN);
    const float* b2p = b2 + gv2 * DN;
    float acc0 = 0.f, acc1 = 0.f;
    #pragma unroll 4
    for (int i = 0; i < 48; ++i) {
        int e = j * 96 + i * 2;
        float4 w4 = *(const float4*)(whp + e * 2);   // (e,l0)(e,l1)(e+1,l0)(e+1,l1)
        float2 bv = *(const float2*)(b2p + e);
        acc0 += bv.x * w4.x + bv.y * w4.z;
        acc1 += bv.x * w4.y + bv.y * w4.w;
    }
    #pragma unroll
    for (int off = 4; off; off >>= 1) {
        acc0 += __shfl_down(acc0, off, 64);
        acc1 += __shfl_down(acc1, off, 64);
    }
    if (j == 0) {
        bc[a * 2 + 0] = acc0 + bh[a * 2 + 0];
        bc[a * 2 + 1] = acc1 + bh[a * 2 + 1];
    }
}

// ---------------------------------------------------------------------------
// k_mid: blockIdx.y < 4  -> h1[g] = pooled @ W1[g] + b1[g]   (bf16 out)
//        blockIdx.y >= 4 -> Wc columns for g2 group (Wcs[a*2+l][d] bf16)
// grid = (12, 12) x 256.
// ---------------------------------------------------------------------------
__global__ __launch_bounds__(256) void k_mid(
    const float* __restrict__ W1, const float* __restrict__ W2,
    const float* __restrict__ Wh, const float* __restrict__ b1,
    const unsigned short* __restrict__ pooled_bf,
    const int* __restrict__ n2, const int* __restrict__ list2,
    unsigned short* __restrict__ h1, unsigned short* __restrict__ Wcs)
{
    __shared__ unsigned short Bs[128 * 40];   // padded stride 40 shorts (80 B)
    const int tid  = threadIdx.x;
    const int lane = tid & 63, wave = tid >> 6;
    const int nn   = lane & 15, quad = lane >> 4;

    if (blockIdx.y < G1N) {
        // ---- h1 = pooled @ W1[g] + b1[g] ----
        const int g = blockIdx.y, e0 = blockIdx.x * 64;
        const float* W1g = W1 + (size_t)g * DN * DN;
        floatx4 acc[4] = {{0,0,0,0},{0,0,0,0},{0,0,0,0},{0,0,0,0}};

        for (int k0 = 0; k0 < DN; k0 += 32) {
            #pragma unroll
            for (int it = 0; it < 2; ++it) {
                int idx = tid + it * 256;        // 0..511
                int row = idx >> 4;              // k rel 0..31
                int c4  = (idx & 15) * 4;        // e rel
                float4 v = *(const float4*)(W1g + (size_t)(k0 + row) * DN + e0 + c4);
                Bs[(c4 + 0) * 40 + row] = f2bf(v.x);
                Bs[(c4 + 1) * 40 + row] = f2bf(v.y);
                Bs[(c4 + 2) * 40 + row] = f2bf(v.z);
                Bs[(c4 + 3) * 40 + row] = f2bf(v.w);
            }
            __syncthreads();
            short8 bf = *(const short8*)(&Bs[(wave * 16 + nn) * 40 + quad * 8]);
            #pragma unroll
            for (int mt = 0; mt < 4; ++mt) {
                short8 af = *(const short8*)(pooled_bf + (size_t)(mt * 16 + nn) * DN + k0 + quad * 8);
                acc[mt] = __builtin_amdgcn_mfma_f32_16x16x32_bf16(af, bf, acc[mt], 0, 0, 0);
            }
            __syncthreads();
        }
        const int e = e0 + wave * 16 + nn;
        const float bv = b1[g * DN + e];
        #pragma unroll
        for (int mt = 0; mt < 4; ++mt)
            #pragma unroll
            for (int r = 0; r < 4; ++r)
                h1[(size_t)g * BN * DN + (size_t)(mt * 16 + quad * 4 + r) * DN + e] =
                    f2bf(acc[mt][r] + bv);
    } else {
        // ---- Wc for g2 group: C[d, c] = sum_e W2[g][d,e] * Wh[a(c)][e,l(c)] ----
        const int g = blockIdx.y - G1N;
        const int mbase = blockIdx.x * 64;
        const float* W2g = W2 + (size_t)g * DN * DN;
        const int cols = 2 * n2[g];
        const int* lst = list2 + g * 256;

        for (int c0 = 0; c0 < cols; c0 += 128) {
            const int cc = min(128, cols - c0);
            const int ntiles = (cc + 15) >> 4;
            floatx4 acc[8] = {{0,0,0,0},{0,0,0,0},{0,0,0,0},{0,0,0,0},
                              {0,0,0,0},{0,0,0,0},{0,0,0,0},{0,0,0,0}};
            for (int k0 = 0; k0 < DN; k0 += 32) {
                for (int idx = tid; idx < cc * 32; idx += 256) {
                    int c = idx >> 5, ee = idx & 31;
                    int cg = c0 + c;
                    int a = lst[cg >> 1], l = cg & 1;
                    Bs[c * 40 + ee] = f2bf(Wh[(size_t)a * (DN * LN) + (k0 + ee) * 2 + l]);
                }
                __syncthreads();
                const float* ap = W2g + (size_t)(mbase + wave * 16 + nn) * DN + k0 + quad * 8;
                float4 a0 = *(const float4*)ap, a1 = *(const float4*)(ap + 4);
                short8 af;
                af[0] = (short)f2bf(a0.x); af[1] = (short)f2bf(a0.y);
                af[2] = (short)f2bf(a0.z); af[3] = (short)f2bf(a0.w);
                af[4] = (short)f2bf(a1.x); af[5] = (short)f2bf(a1.y);
                af[6] = (short)f2bf(a1.z); af[7] = (short)f2bf(a1.w);
                #pragma unroll
                for (int nt = 0; nt < 8; ++nt) {
                    if (nt >= ntiles) break;
                    short8 bf = *(const short8*)(&Bs[(nt * 16 + nn) * 40 + quad * 8]);
                    acc[nt] = __builtin_amdgcn_mfma_f32_16x16x32_bf16(af, bf, acc[nt], 0, 0, 0);
                }
                __syncthreads();
            }
            for (int nt = 0; nt < ntiles; ++nt) {
                int c = c0 + nt * 16 + nn;
                if (c < cols) {
                    int a = lst[c >> 1], l = c & 1;
                    int d0 = mbase + wave * 16 + quad * 4;
                    bf16x4 v;
                    #pragma unroll
                    for (int r = 0; r < 4; ++r) v[r] = (short)f2bf(acc[nt][r]);
                    *(bf16x4*)(Wcs + (size_t)(a * 2 + l) * DN + d0) = v;
                }
            }
        }
    }
}

// ---------------------------------------------------------------------------
// k_last: out[b, a, l] = h1[g1(a)][b,:] . Wcs[a*2+l][:] + bc[a*2+l]
// grid = (32 n-tile slots, 4 g1 groups) x 256; extra blocks exit early.
// ---------------------------------------------------------------------------
__global__ __launch_bounds__(256) void k_last(
    const unsigned short* __restrict__ h1, const unsigned short* __restrict__ Wcs,
    const float* __restrict__ bc, const int* __restrict__ n1,
    const int* __restrict__ list1, float* __restrict__ out)
{
    const int g = blockIdx.y;
    const int cols = 2 * n1[g];
    const int nt0 = blockIdx.x * 16;
    if (nt0 >= cols) return;

    const int tid = threadIdx.x;
    const int lane = tid & 63, wave = tid >> 6;
    const int nn = lane & 15, quad = lane >> 4;

    const int c = nt0 + nn;
    const bool valid = (c < cols);
    const int cl = valid ? c : (cols - 1);
    const int a = list1[g * 256 + (cl >> 1)];
    const int colid = a * 2 + (cl & 1);

    const unsigned short* hg = h1 + (size_t)g * BN * DN + (size_t)(wave * 16 + nn) * DN;
    const unsigned short* wp = Wcs + (size_t)colid * DN;

    floatx4 acc = {0, 0, 0, 0};
    for (int k0 = 0; k0 < DN; k0 += 32) {
        short8 af = *(const short8*)(hg + k0 + quad * 8);
        short8 bf = *(const short8*)(wp + k0 + quad * 8);
        acc = __builtin_amdgcn_mfma_f32_16x16x32_bf16(af, bf, acc, 0, 0, 0);
    }
    if (valid) {
        const float bv = bc[colid];
        #pragma unroll
        for (int r = 0; r < 4; ++r)
            out[(size_t)(wave * 16 + quad * 4 + r) * (AN * LN) + colid] = acc[r] + bv;
    }
}

extern "C" void kernel_launch(void* const* d_in, const int* in_sizes, int n_in,
                              void* d_out, int out_size, void* d_ws, size_t ws_size,
                              hipStream_t stream) {
    const float* pooled = (const float*)d_in[0];
    const float* W1     = (const float*)d_in[1];
    const float* b1     = (const float*)d_in[2];
    const float* W2     = (const float*)d_in[3];
    const float* b2     = (const float*)d_in[4];
    const float* Wh     = (const float*)d_in[5];
    const float* bh     = (const float*)d_in[6];
    const int*   g1i    = (const int*)d_in[7];
    const int*   g2i    = (const int*)d_in[8];
    float* out = (float*)d_out;

    // Workspace carve (16B-aligned offsets): bc | n1 | n2 | list1 | list2 |
    // pooled_bf | h1 | Wcs   (~1.3 MB total)
    char* ws = (char*)d_ws;
    float* bc   = (float*)ws;             ws += 512 * 4;
    int*   n1   = (int*)ws;               ws += 4 * 4;
    int*   n2   = (int*)ws;               ws += 8 * 4;
    int*   lst1 = (int*)ws;               ws += 4 * 256 * 4;
    int*   lst2 = (int*)ws;               ws += 8 * 256 * 4;
    unsigned short* pooled_bf = (unsigned short*)ws;  ws += (size_t)BN * DN * 2;
    unsigned short* h1        = (unsigned short*)ws;  ws += (size_t)G1N * BN * DN * 2;
    unsigned short* Wcs       = (unsigned short*)ws;

    dim3 blk(256);
    kb    <<<dim3(8),      blk, 0, stream>>>(pooled, b2, Wh, bh, g1i, g2i,
                                             n1, n2, lst1, lst2, bc, pooled_bf);
    k_mid <<<dim3(12, 12), blk, 0, stream>>>(W1, W2, Wh, b1, pooled_bf,
                                             n2, lst2, h1, Wcs);
    k_last<<<dim3(32, 4),  blk, 0, stream>>>(h1, Wcs, bc, n1, lst1, out);
}

// Round 5
// 136.716 us; speedup vs baseline: 1.4548x; 1.4548x over previous
//
#include <hip/hip_runtime.h>
#include <hip/hip_bf16.h>

#define AN 256
#define BN 64
#define DN 768
#define LN 2
#define G1N 4
#define G2N 8
#define KI (DN / 32)   // 24 k-iterations of 32

typedef __attribute__((ext_vector_type(8))) short short8;   // 8 bf16
typedef __attribute__((ext_vector_type(4))) short bf16x4;   // 4 bf16
typedef __attribute__((ext_vector_type(4))) float floatx4;  // MFMA acc

static __device__ __forceinline__ unsigned short f2bf(float f) {
    union { float f; unsigned int u; } v; v.f = f;
    unsigned int r = v.u + 0x7FFF + ((v.u >> 16) & 1);  // RNE
    return (unsigned short)(r >> 16);
}

// ---------------------------------------------------------------------------
// k_prep: 1D grid of 841 blocks x 256, all independent jobs:
//   bx <  576 : W1 transpose tile -> W1t[g][e][d] bf16 (g=bx/144)
//   576..583  : pooled->bf16 slice + bc for 32 annotators
//   bx == 584 : g1 lists (n1,lst1), n2 counts, sidx2 LUT
//   585..840  : pack Wh[a] -> Whp[(g2*128+s)*2+l][e] bf16 (a = bx-585)
// ---------------------------------------------------------------------------
__global__ __launch_bounds__(256) void k_prep(
    const float* __restrict__ pooled, const float* __restrict__ W1,
    const float* __restrict__ b2, const float* __restrict__ Wh,
    const float* __restrict__ bh,
    const int* __restrict__ g1i, const int* __restrict__ g2i,
    unsigned short* __restrict__ W1t, unsigned short* __restrict__ Whp,
    unsigned short* __restrict__ pooled_bf, float* __restrict__ bc,
    int* __restrict__ n1, int* __restrict__ n2,
    int* __restrict__ lst1, int* __restrict__ sidx2)
{
    const int tid = threadIdx.x, bx = blockIdx.x;

    if (bx < 576) {
        // ---- W1 transpose: W1t[g][e][d] = bf16(W1[g][d][e]) ----
        const int g = bx / 144, t = bx % 144;
        const int d0 = (t / 12) * 64, e0 = (t % 12) * 64;
        const float* src = W1 + (size_t)g * DN * DN;
        __shared__ float tile[64][65];
        const int r = tid >> 4, c = (tid & 15) * 4;
        #pragma unroll
        for (int i = 0; i < 4; ++i) {
            float4 v = *(const float4*)(src + (size_t)(d0 + r + 16 * i) * DN + e0 + c);
            tile[r + 16 * i][c + 0] = v.x; tile[r + 16 * i][c + 1] = v.y;
            tile[r + 16 * i][c + 2] = v.z; tile[r + 16 * i][c + 3] = v.w;
        }
        __syncthreads();
        #pragma unroll
        for (int i = 0; i < 4; ++i) {
            bf16x4 v;
            #pragma unroll
            for (int j = 0; j < 4; ++j) v[j] = (short)f2bf(tile[c + j][r + 16 * i]);
            *(bf16x4*)(W1t + ((size_t)g * DN + e0 + r + 16 * i) * DN + d0 + c) = v;
        }
        return;
    }

    if (bx < 584) {
        const int i0 = (bx - 576) * 6144;
        for (int i = i0 + tid; i < i0 + 6144; i += 256)
            pooled_bf[i] = f2bf(pooled[i]);

        // bc: 32 annotators per block, 8 threads per annotator
        const int aa = tid >> 3, j = tid & 7;
        const int a = (bx - 576) * 32 + aa;
        const int gv2 = g2i[a];
        const float* whp = Wh + (size_t)a * (DN * LN);
        const float* b2p = b2 + gv2 * DN;
        float acc0 = 0.f, acc1 = 0.f;
        #pragma unroll 4
        for (int i = 0; i < 48; ++i) {
            int e = j * 96 + i * 2;
            float4 w4 = *(const float4*)(whp + e * 2);
            float2 bv = *(const float2*)(b2p + e);
            acc0 += bv.x * w4.x + bv.y * w4.z;
            acc1 += bv.x * w4.y + bv.y * w4.w;
        }
        #pragma unroll
        for (int off = 4; off; off >>= 1) {
            acc0 += __shfl_down(acc0, off, 64);
            acc1 += __shfl_down(acc1, off, 64);
        }
        if (j == 0) {
            bc[a * 2 + 0] = acc0 + bh[a * 2 + 0];
            bc[a * 2 + 1] = acc1 + bh[a * 2 + 1];
        }
        return;
    }

    if (bx == 584) {
        __shared__ int g1s[AN], g2s[AN];
        __shared__ int c1s[G1N], c2s[G2N];
        g1s[tid] = g1i[tid];
        g2s[tid] = g2i[tid];
        if (tid < G1N) c1s[tid] = 0;
        if (tid < G2N) c2s[tid] = 0;
        __syncthreads();
        // deterministic sidx2 (must match pack blocks' computation)
        int s = 0, my2 = g2s[tid];
        for (int a2 = 0; a2 < tid; ++a2) s += (g2s[a2] == my2);
        sidx2[tid] = s;
        atomicAdd(&c2s[my2], 1);
        int p1 = atomicAdd(&c1s[g1s[tid]], 1);
        lst1[g1s[tid] * 256 + p1] = tid;
        __syncthreads();
        if (tid < G1N) n1[tid] = c1s[tid];
        if (tid < G2N) n2[tid] = c2s[tid];
        return;
    }

    // ---- pack Wh[a] into Whp rows (g2-bucketed, l-de-interleaved) ----
    {
        const int a = bx - 585;
        __shared__ int g2s[AN];
        g2s[tid] = g2i[tid];
        __syncthreads();
        int s = 0, my2 = g2s[a];
        for (int a2 = 0; a2 < a; ++a2) s += (g2s[a2] == my2);
        const size_t rp = ((size_t)my2 * 128 + s) * 2;
        const float* wa = Wh + (size_t)a * (DN * LN);
        #pragma unroll
        for (int i = 0; i < 3; ++i) {
            int e = i * 256 + tid;
            float2 v = *(const float2*)(wa + e * 2);
            Whp[rp * DN + e]       = f2bf(v.x);
            Whp[(rp + 1) * DN + e] = f2bf(v.y);
        }
    }
}

// ---------------------------------------------------------------------------
// k_mid: grid (12, 12) x 256. No LDS, no barriers.
//  y <  4: h1[g][b][e] = pooled @ W1[g] + b1[g]  (bf16), A/B direct global.
//  y >= 4: Wc for g2 group g=y-4: Wcs[g*256 + c][d] = sum_e W2[g][d,e]*Whp[..c..][e]
//          A (W2 rows, 64 d per block) held in VGPRs across column tiles.
// ---------------------------------------------------------------------------
__global__ __launch_bounds__(256) void k_mid(
    const float* __restrict__ W2, const float* __restrict__ b1,
    const unsigned short* __restrict__ W1t,
    const unsigned short* __restrict__ Whp,
    const unsigned short* __restrict__ pooled_bf,
    const int* __restrict__ n2,
    unsigned short* __restrict__ h1, unsigned short* __restrict__ Wcs)
{
    const int tid  = threadIdx.x;
    const int lane = tid & 63, wave = tid >> 6;
    const int nn   = lane & 15, quad = lane >> 4;

    if (blockIdx.y < G1N) {
        // ---- h1 = pooled @ W1[g] + b1[g] ----
        const int g = blockIdx.y, e0 = blockIdx.x * 64;
        const int e = e0 + wave * 16 + nn;
        const unsigned short* Bt = W1t + ((size_t)g * DN + e) * DN + quad * 8;
        const unsigned short* Ap = pooled_bf + (size_t)nn * DN + quad * 8;
        floatx4 acc[4] = {{0,0,0,0},{0,0,0,0},{0,0,0,0},{0,0,0,0}};
        #pragma unroll
        for (int kk = 0; kk < KI; ++kk) {
            short8 bf = *(const short8*)(Bt + kk * 32);
            #pragma unroll
            for (int mt = 0; mt < 4; ++mt) {
                short8 af = *(const short8*)(Ap + (size_t)(mt * 16) * DN + kk * 32);
                acc[mt] = __builtin_amdgcn_mfma_f32_16x16x32_bf16(af, bf, acc[mt], 0, 0, 0);
            }
        }
        const float bv = b1[g * DN + e];
        #pragma unroll
        for (int mt = 0; mt < 4; ++mt)
            #pragma unroll
            for (int r = 0; r < 4; ++r)
                h1[(size_t)g * BN * DN + (size_t)(mt * 16 + quad * 4 + r) * DN + e] =
                    f2bf(acc[mt][r] + bv);
    } else {
        // ---- Wc: A = W2 rows in regs; stream packed Whp columns ----
        const int g = blockIdx.y - G1N;
        const int mbase = blockIdx.x * 64;
        const int cols = 2 * n2[g];
        const int m_row = mbase + wave * 16 + nn;

        const float* ap = W2 + ((size_t)g * DN + m_row) * DN + quad * 8;
        short8 Areg[KI];
        #pragma unroll
        for (int kk = 0; kk < KI; ++kk) {
            float4 a0 = *(const float4*)(ap + kk * 32);
            float4 a1 = *(const float4*)(ap + kk * 32 + 4);
            short8 af;
            af[0] = (short)f2bf(a0.x); af[1] = (short)f2bf(a0.y);
            af[2] = (short)f2bf(a0.z); af[3] = (short)f2bf(a0.w);
            af[4] = (short)f2bf(a1.x); af[5] = (short)f2bf(a1.y);
            af[6] = (short)f2bf(a1.z); af[7] = (short)f2bf(a1.w);
            Areg[kk] = af;
        }

        const unsigned short* Bbase = Whp + (size_t)(g * 256) * DN;
        for (int c0 = 0; c0 < cols; c0 += 16) {
            const unsigned short* Brow = Bbase + (size_t)(c0 + nn) * DN + quad * 8;
            floatx4 acc = {0, 0, 0, 0};
            #pragma unroll
            for (int kk = 0; kk < KI; ++kk) {
                short8 bf = *(const short8*)(Brow + kk * 32);
                acc = __builtin_amdgcn_mfma_f32_16x16x32_bf16(Areg[kk], bf, acc, 0, 0, 0);
            }
            const int c = c0 + nn;
            if (c < cols) {
                const int dbase = mbase + wave * 16 + quad * 4;
                bf16x4 v;
                #pragma unroll
                for (int r = 0; r < 4; ++r) v[r] = (short)f2bf(acc[r]);
                *(bf16x4*)(Wcs + (size_t)(g * 256 + c) * DN + dbase) = v;
            }
        }
    }
}

// ---------------------------------------------------------------------------
// k_last: out[b, a, l] = h1[g1(a)][b,:] . Wcs[(g2(a)*128+s2(a))*2+l][:] + bc
// grid = (32, 4) x 256; extra column-tiles exit early.
// ---------------------------------------------------------------------------
__global__ __launch_bounds__(256) void k_last(
    const unsigned short* __restrict__ h1, const unsigned short* __restrict__ Wcs,
    const float* __restrict__ bc, const int* __restrict__ n1,
    const int* __restrict__ lst1, const int* __restrict__ sidx2,
    const int* __restrict__ g2i, float* __restrict__ out)
{
    const int g = blockIdx.y;
    const int cols = 2 * n1[g];
    const int nt0 = blockIdx.x * 16;
    if (nt0 >= cols) return;

    const int tid = threadIdx.x;
    const int lane = tid & 63, wave = tid >> 6;
    const int nn = lane & 15, quad = lane >> 4;

    const int c = nt0 + nn;
    const bool valid = (c < cols);
    const int cl = valid ? c : (cols - 1);
    const int a = lst1[g * 256 + (cl >> 1)];
    const int l = cl & 1;
    const int rp = (g2i[a] * 128 + sidx2[a]) * 2 + l;

    const unsigned short* hg = h1 + (size_t)g * BN * DN + (size_t)(wave * 16 + nn) * DN + quad * 8;
    const unsigned short* wp = Wcs + (size_t)rp * DN + quad * 8;

    floatx4 acc = {0, 0, 0, 0};
    #pragma unroll
    for (int kk = 0; kk < KI; ++kk) {
        short8 af = *(const short8*)(hg + kk * 32);
        short8 bf = *(const short8*)(wp + kk * 32);
        acc = __builtin_amdgcn_mfma_f32_16x16x32_bf16(af, bf, acc, 0, 0, 0);
    }
    if (valid) {
        const float bv = bc[a * 2 + l];
        #pragma unroll
        for (int r = 0; r < 4; ++r)
            out[(size_t)(wave * 16 + quad * 4 + r) * (AN * LN) + a * 2 + l] = acc[r] + bv;
    }
}

extern "C" void kernel_launch(void* const* d_in, const int* in_sizes, int n_in,
                              void* d_out, int out_size, void* d_ws, size_t ws_size,
                              hipStream_t stream) {
    const float* pooled = (const float*)d_in[0];
    const float* W1     = (const float*)d_in[1];
    const float* b1     = (const float*)d_in[2];
    const float* W2     = (const float*)d_in[3];
    const float* b2     = (const float*)d_in[4];
    const float* Wh     = (const float*)d_in[5];
    const float* bh     = (const float*)d_in[6];
    const int*   g1i    = (const int*)d_in[7];
    const int*   g2i    = (const int*)d_in[8];
    float* out = (float*)d_out;

    // Workspace carve (all chunks 16B-multiple): ~11.7 MB total
    char* ws = (char*)d_ws;
    float* bc   = (float*)ws;             ws += 512 * 4;
    int*   n1   = (int*)ws;               ws += 4 * 4;
    int*   n2   = (int*)ws;               ws += 8 * 4;      // (16B-aligned ok: 16+32)
    int*   lst1 = (int*)ws;               ws += 4 * 256 * 4;
    int*   sidx2= (int*)ws;               ws += 256 * 4;
    unsigned short* pooled_bf = (unsigned short*)ws;  ws += (size_t)BN * DN * 2;
    unsigned short* h1        = (unsigned short*)ws;  ws += (size_t)G1N * BN * DN * 2;
    unsigned short* W1t       = (unsigned short*)ws;  ws += (size_t)G1N * DN * DN * 2;
    unsigned short* Whp       = (unsigned short*)ws;  ws += (size_t)G2N * 256 * DN * 2;
    unsigned short* Wcs       = (unsigned short*)ws;

    dim3 blk(256);
    k_prep<<<dim3(841),    blk, 0, stream>>>(pooled, W1, b2, Wh, bh, g1i, g2i,
                                             W1t, Whp, pooled_bf, bc, n1, n2, lst1, sidx2);
    k_mid <<<dim3(12, 12), blk, 0, stream>>>(W2, b1, W1t, Whp, pooled_bf, n2, h1, Wcs);
    k_last<<<dim3(32, 4),  blk, 0, stream>>>(h1, Wcs, bc, n1, lst1, sidx2, g2i, out);
}